// Round 3
// baseline (63.730 us; speedup 1.0000x reference)
//
#include <hip/hip_runtime.h>

// IndirectLearningDPD: GMP basis + complex matmul, factored into an 8-tap
// complex stencil.
//
// y[n] = sum_{d=0..3} x[n-d] * C_d(n-d), where for m = n-d:
//   C_d(m) = c[0+d]            (order 1, r = 1)
//          + c[4+d]*a2[m]  + c[8+d]*a4[m]  + c[12+d]*a6[m]      (main, orders 3/5/7)
//          + c[16+d]*a2[m-1] + c[20+d]*a2[m-2]                  (lag,  order 3)
//          + c[24+d]*a4[m-1] + c[28+d]*a4[m-2]                  (lag,  order 5)
//          + c[32+d]*a6[m-1] + c[36+d]*a6[m-2]                  (lag,  order 7)
//          + c[40+d]*a2[m+1] + c[44+d]*a2[m+2]                  (lead, order 3)
//          + c[48+d]*a4[m+1] + c[52+d]*a4[m+2]                  (lead, order 5)
//          + c[56+d]*a6[m+1] + c[60+d]*a6[m+2]                  (lead, order 7)
// with a2 = |x|^2 (even powers only -> no sqrt) and all out-of-range
// positions contributing exact zeros (matches the reference's zero padding).
//
// ABI findings (R1/R2): out_size = 2*B*S floats; complex64 output expected
// PLANAR — out[0:N] = real part, out[N:2N] = imag part (R2's interleaved
// layout gave absmax 2.03 ≈ |y_r|+|y_i| signature). R1 crash was a flake.

constexpr int BLOCK  = 256;
constexpr int HALO_L = 5;  // need m down to n-3-2
constexpr int HALO_R = 2;  // need m up to n+2
constexpr int TILE   = BLOCK + HALO_L + HALO_R;  // 263

__global__ __launch_bounds__(BLOCK) void dpd_gmp_kernel(
    const float* __restrict__ xr, const float* __restrict__ xi,
    const float* __restrict__ cr, const float* __restrict__ ci,
    float* __restrict__ out, int N, int out_size)
{
    __shared__ float sxr[TILE];
    __shared__ float sxi[TILE];

    const int tid  = threadIdx.x;
    const int base = blockIdx.x * BLOCK;

    // Stage window m in [base-5, base+257] into LDS; zero-pad out of range.
    for (int k = tid; k < TILE; k += BLOCK) {
        int m = base - HALO_L + k;
        bool ok = (m >= 0) && (m < N);
        sxr[k] = ok ? xr[m] : 0.0f;
        sxi[k] = ok ? xi[m] : 0.0f;
    }
    __syncthreads();

    const int n = base + tid;

    // Window registers: w in [0,8) maps to m = n-5+w (LDS index tid+w).
    float wr[8], wi[8], p2[8], p4[8], p6[8];
#pragma unroll
    for (int w = 0; w < 8; ++w) {
        wr[w] = sxr[tid + w];
        wi[w] = sxi[tid + w];
        float s = wr[w] * wr[w] + wi[w] * wi[w];
        p2[w] = s;
        p4[w] = s * s;
        p6[w] = p4[w] * s;
    }

    float yr = 0.0f, yi = 0.0f;
#pragma unroll
    for (int d = 0; d < 4; ++d) {
        const int i = HALO_L - d;  // window index of m = n-d

        float Cr = cr[0 + d];
        float Ci = ci[0 + d];
        Cr = fmaf(cr[ 4 + d], p2[i],     Cr);  Ci = fmaf(ci[ 4 + d], p2[i],     Ci);
        Cr = fmaf(cr[ 8 + d], p4[i],     Cr);  Ci = fmaf(ci[ 8 + d], p4[i],     Ci);
        Cr = fmaf(cr[12 + d], p6[i],     Cr);  Ci = fmaf(ci[12 + d], p6[i],     Ci);
        Cr = fmaf(cr[16 + d], p2[i - 1], Cr);  Ci = fmaf(ci[16 + d], p2[i - 1], Ci);
        Cr = fmaf(cr[20 + d], p2[i - 2], Cr);  Ci = fmaf(ci[20 + d], p2[i - 2], Ci);
        Cr = fmaf(cr[24 + d], p4[i - 1], Cr);  Ci = fmaf(ci[24 + d], p4[i - 1], Ci);
        Cr = fmaf(cr[28 + d], p4[i - 2], Cr);  Ci = fmaf(ci[28 + d], p4[i - 2], Ci);
        Cr = fmaf(cr[32 + d], p6[i - 1], Cr);  Ci = fmaf(ci[32 + d], p6[i - 1], Ci);
        Cr = fmaf(cr[36 + d], p6[i - 2], Cr);  Ci = fmaf(ci[36 + d], p6[i - 2], Ci);
        Cr = fmaf(cr[40 + d], p2[i + 1], Cr);  Ci = fmaf(ci[40 + d], p2[i + 1], Ci);
        Cr = fmaf(cr[44 + d], p2[i + 2], Cr);  Ci = fmaf(ci[44 + d], p2[i + 2], Ci);
        Cr = fmaf(cr[48 + d], p4[i + 1], Cr);  Ci = fmaf(ci[48 + d], p4[i + 1], Ci);
        Cr = fmaf(cr[52 + d], p4[i + 2], Cr);  Ci = fmaf(ci[52 + d], p4[i + 2], Ci);
        Cr = fmaf(cr[56 + d], p6[i + 1], Cr);  Ci = fmaf(ci[56 + d], p6[i + 1], Ci);
        Cr = fmaf(cr[60 + d], p6[i + 2], Cr);  Ci = fmaf(ci[60 + d], p6[i + 2], Ci);

        // y += x[n-d] * C_d   (complex multiply-accumulate).
        // x[n-d] is zero-staged for n-d < 0, which kills the whole column
        // including the order-1 constant term — matches reference delay pad.
        yr = fmaf(wr[i],  Cr, yr);
        yr = fmaf(-wi[i], Ci, yr);
        yi = fmaf(wr[i],  Ci, yi);
        yi = fmaf(wi[i],  Cr, yi);
    }

    // PLANAR complex64 output: out[0:N] = real, out[N:2N] = imag.
    // Both streams fully coalesced. Guards keep any ABI surprise non-fatal.
    if (n < N) {
        if (n < out_size)     out[n]     = yr;
        if (N + n < out_size) out[N + n] = yi;
    }
}

extern "C" void kernel_launch(void* const* d_in, const int* in_sizes, int n_in,
                              void* d_out, int out_size, void* d_ws, size_t ws_size,
                              hipStream_t stream) {
    const float* xr = (const float*)d_in[0];
    const float* xi = (const float*)d_in[1];
    const float* cr = (const float*)d_in[2];
    const float* ci = (const float*)d_in[3];
    float* out = (float*)d_out;

    const int N = in_sizes[0];  // B*S flattened signal length
    const int grid = (N + BLOCK - 1) / BLOCK;
    dpd_gmp_kernel<<<grid, BLOCK, 0, stream>>>(xr, xi, cr, ci, out, N, out_size);
}